// Round 5
// baseline (1029.060 us; speedup 1.0000x reference)
//
#include <hip/hip_runtime.h>

typedef __bf16 bf16_t;
typedef __bf16 bf16x8 __attribute__((ext_vector_type(8)));
typedef float f32x4 __attribute__((ext_vector_type(4)));
typedef int   int4v __attribute__((ext_vector_type(4)));

#define LOG2E 1.4426950408889634f
#define NBLK  256

template<int CTRL>
__device__ __forceinline__ float qperm(float x) {
  return __builtin_bit_cast(float,
      __builtin_amdgcn_update_dpp(0, __builtin_bit_cast(int, x), CTRL, 0xF, 0xF, true));
}

// LDS-only barrier: does NOT drain vmcnt, so global loads/stores stay in
// flight across steps (compiler's __syncthreads drains vmcnt(0) every step).
__device__ __forceinline__ void lds_barrier() {
  asm volatile("s_waitcnt lgkmcnt(0)\n\ts_barrier" ::: "memory");
}

// Device-scope grid barrier.  All NBLK blocks are co-resident by capacity
// (grid = 256 = #CUs, 1 block/CU worst case -> every block is scheduled).
// Release-add publishes prior writes; acquire-load synchronizes-with ALL
// blocks' adds once count reaches target (agent scope -> cross-XCD safe).
__device__ __forceinline__ void gridbar(unsigned* cnt, unsigned target) {
  __syncthreads();
  if (threadIdx.x == 0) {
    __threadfence();
    __hip_atomic_fetch_add(cnt, 1u, __ATOMIC_RELEASE, __HIP_MEMORY_SCOPE_AGENT);
    while (__hip_atomic_load(cnt, __ATOMIC_ACQUIRE, __HIP_MEMORY_SCOPE_AGENT)
           < target)
      __builtin_amdgcn_s_sleep(16);
  }
  __syncthreads();
}

// ---------------------------------------------------------------------------
// Single fused kernel, 4 phases separated by grid barriers:
//   P0 pre   : preT = Wih@x + biases (gate-interleaved rows), 256 blocks
//   P1 lstm  : sequential recurrence, blocks 0,1 only (others spin)
//   P2 qgemm : Ea/Eb = exp2(C2 * (h@W1.T [+b1])), 2048 wave-jobs
//   P3 outer : out = b2 + sum_k W2[k]*tanh(.), 512 half-block jobs
// Fusion removes 3 inter-kernel launch gaps (~20us each in this harness).
// ---------------------------------------------------------------------------
__global__ __launch_bounds__(512) void fused_kernel(
    const float* __restrict__ x,     // [512][125]
    const float* __restrict__ Wih_f, const float* __restrict__ bih_f,
    const float* __restrict__ bhh_f,
    const float* __restrict__ Wih_b, const float* __restrict__ bih_b,
    const float* __restrict__ bhh_b,
    const float* __restrict__ Whh_f, const float* __restrict__ Whh_b,
    const float* __restrict__ W1,    const float* __restrict__ b1,
    const float* __restrict__ W2,    const float* __restrict__ b2,
    float* __restrict__ preT,        // [2][512 r][512 t]
    bf16_t* __restrict__ h_all,      // [512][256]
    float* __restrict__ Ea,          // [512][512]
    float* __restrict__ Eb,          // [512][512]
    unsigned* __restrict__ cnt,
    float* __restrict__ out)         // [512][512]
{
  const int tid  = threadIdx.x;
  const int wv   = tid >> 6;        // wave 0..7
  const int lane = tid & 63;
  const int q    = lane >> 4, cc = lane & 15;

  // ===================== P0: pre =====================
  {
    const int b   = blockIdx.x;
    const int dir = b >> 7;
    const int T   = (b >> 2) & 31;
    const int tq  = b & 3;
    const float* __restrict__ Wih = dir ? Wih_b : Wih_f;
    const float* __restrict__ bih = dir ? bih_b : bih_f;
    const float* __restrict__ bhh = dir ? bhh_b : bhh_f;

    // A fragments for row-tile T: row r = 16T + cc, k = 32ks + 8q + j
    const int r  = 16 * T + cc;
    const int na = r >> 2, pa = r & 3;
    const bool vld = (na < 125);
    const float* __restrict__ Wr = Wih + (vld ? (125 * pa + na) * 125 : 0);

    bf16x8 whi[4], wlo[4];
    #pragma unroll
    for (int ks = 0; ks < 4; ++ks) {
      #pragma unroll
      for (int j = 0; j < 8; ++j) {
        int k = 32 * ks + 8 * q + j;
        float wvv = (vld && k < 125) ? Wr[k] : 0.0f;
        bf16_t hi = (bf16_t)wvv;
        whi[ks][j] = hi;
        wlo[ks][j] = (bf16_t)(wvv - (float)hi);
      }
    }

    float bias[4];
    #pragma unroll
    for (int reg = 0; reg < 4; ++reg) {
      int ro = 16 * T + 4 * q + reg;
      int no = ro >> 2, po = ro & 3;
      bias[reg] = (no < 125) ? (bih[125 * po + no] + bhh[125 * po + no]) : 0.0f;
    }

    const int tt = 8 * tq + wv;          // one t-tile per wave
    const int t  = 16 * tt + cc;
    const int trow = dir ? (511 - t) : t;
    const float* __restrict__ xr = x + trow * 125;

    f32x4 acc = (f32x4)0.0f;
    #pragma unroll
    for (int ks = 0; ks < 4; ++ks) {
      bf16x8 xhi, xlo;
      #pragma unroll
      for (int j = 0; j < 8; ++j) {
        int k = 32 * ks + 8 * q + j;
        float xv = (k < 125) ? xr[k] : 0.0f;
        bf16_t hi = (bf16_t)xv;
        xhi[j] = hi;
        xlo[j] = (bf16_t)(xv - (float)hi);
      }
      acc = __builtin_amdgcn_mfma_f32_16x16x32_bf16(whi[ks], xhi, acc, 0, 0, 0);
      acc = __builtin_amdgcn_mfma_f32_16x16x32_bf16(whi[ks], xlo, acc, 0, 0, 0);
      acc = __builtin_amdgcn_mfma_f32_16x16x32_bf16(wlo[ks], xhi, acc, 0, 0, 0);
    }
    #pragma unroll
    for (int reg = 0; reg < 4; ++reg) {
      int ro = 16 * T + 4 * q + reg;
      preT[dir * 262144 + ro * 512 + 16 * tt + cc] = acc[reg] + bias[reg];
    }
  }

  gridbar(cnt, NBLK);

  // ===================== P1: lstm (blocks 0,1) =====================
  __shared__ float wmx[8];
  __shared__ __align__(16) char hbuf[2][128];

  if (blockIdx.x < 2) {
    const int dir = blockIdx.x;
    const float* __restrict__ Whh = dir ? Whh_b : Whh_f;

    const int w  = wv;
    const int lt = cc >> 2;
    const int p  = cc & 3;

    // pass 1: global max |Whh|
    float wm = 0.0f;
    #pragma unroll
    for (int LT = 0; LT < 4; ++LT) {
      int rr = 16 * (4 * w + LT) + cc;
      int nn = rr >> 2, pp = rr & 3;
      if (nn < 125) {
        const float* __restrict__ Wrow = Whh + (125 * pp + nn) * 125;
        #pragma unroll
        for (int ks = 0; ks < 2; ++ks)
          #pragma unroll
          for (int jj = 0; jj < 16; ++jj) {
            int k = 64 * ks + 16 * q + jj;
            if (k < 125) wm = fmaxf(wm, fabsf(Wrow[k]));
          }
      }
    }
    #pragma unroll
    for (int off = 1; off < 64; off <<= 1)
      wm = fmaxf(wm, __shfl_xor(wm, off));
    if (lane == 0) wmx[w] = wm;
    __syncthreads();
    float wmax = wmx[0];
    #pragma unroll
    for (int u = 1; u < 8; ++u) wmax = fmaxf(wmax, wmx[u]);
    const float s_w  = 127.0f / wmax;
    const float invq = wmax / (127.0f * 127.0f);

    // pass 2: quantize A fragments
    int4v afrag[4][2];
    #pragma unroll
    for (int LT = 0; LT < 4; ++LT) {
      int rr = 16 * (4 * w + LT) + cc;
      int nn = rr >> 2, pp = rr & 3;
      bool avld = (nn < 125);
      const float* __restrict__ Wrow = Whh + (avld ? (125 * pp + nn) * 125 : 0);
      #pragma unroll
      for (int ks = 0; ks < 2; ++ks) {
        int4v v;
        #pragma unroll
        for (int word = 0; word < 4; ++word) {
          int bb = 0;
          #pragma unroll
          for (int byte = 0; byte < 4; ++byte) {
            int jj = 4 * word + byte;
            int k  = 64 * ks + 16 * q + jj;
            int qv = 0;
            if (avld && k < 125)
              qv = (int)__builtin_rintf(Wrow[k] * s_w);
            bb |= (qv & 0xFF) << (8 * byte);
          }
          v[word] = bb;
        }
        afrag[LT][ks] = v;
      }
    }

    if (tid < 256) hbuf[tid >> 7][tid & 127] = 0;
    if (dir == 0) {
      #pragma unroll
      for (int u = 0; u < 6; ++u) h_all[tid * 256 + 250 + u] = (bf16_t)0.0f;
    }
    __syncthreads();

    const int   r_lane = 64 * w + 16 * lt + 4 * q + p;
    const int   nset   = 16 * w + 4 * lt + q;
    const float mult   = (p == 2) ? (-2.0f * LOG2E) : (-LOG2E);
    const float sA     = (p == 2) ? 2.0f : 1.0f;
    const float sB     = (p == 2) ? -1.0f : 0.0f;
    const float dscale = mult * invq;
    const float* __restrict__ preR = preT + dir * 262144 + r_lane * 512;
    float c = 0.0f;

    float4 pv_cur = *(const float4*)preR;

    for (int g = 0; g < 128; ++g) {
      float4 pv_nxt = make_float4(0.f, 0.f, 0.f, 0.f);
      if (g < 127) pv_nxt = *(const float4*)(preR + 4 * (g + 1));

      #pragma unroll
      for (int s4 = 0; s4 < 4; ++s4) {
        const int step = 4 * g + s4;
        const int cur  = s4 & 1, nxt = cur ^ 1;
        const float pv = (s4 == 0) ? pv_cur.x : (s4 == 1) ? pv_cur.y
                       : (s4 == 2) ? pv_cur.z : pv_cur.w;
        const float pvm = mult * pv;

        int4v b0 = *(const int4v*)&hbuf[cur][16 * q];
        int4v b1 = *(const int4v*)&hbuf[cur][64 + 16 * q];

        int4v acc[4];
        #pragma unroll
        for (int LT = 0; LT < 4; ++LT) {
          int4v a = (int4v)0;
          a = __builtin_amdgcn_mfma_i32_16x16x64_i8(afrag[LT][0], b0, a, 0, 0, 0);
          a = __builtin_amdgcn_mfma_i32_16x16x64_i8(afrag[LT][1], b1, a, 0, 0, 0);
          acc[LT] = a;
        }

        int gl[4];
        #pragma unroll
        for (int LT = 0; LT < 4; ++LT) {
          int a01 = (p & 1) ? acc[LT][1] : acc[LT][0];
          int a23 = (p & 1) ? acc[LT][3] : acc[LT][2];
          gl[LT] = (p & 2) ? a23 : a01;
        }
        int b01 = (lt & 1) ? gl[1] : gl[0];
        int b23 = (lt & 1) ? gl[3] : gl[2];
        int gsel = (lt & 2) ? b23 : b01;

        float gf  = (float)gsel;
        float xg  = fmaf(gf, dscale, pvm);
        float e   = __builtin_amdgcn_exp2f(xg);
        float y   = __builtin_amdgcn_rcpf(1.0f + e);
        float act = fmaf(y, sA, sB);

        float b_i = qperm<0x00>(act);
        float b_f = qperm<0x55>(act);
        float b_g = qperm<0xAA>(act);
        float b_o = qperm<0xFF>(act);
        c = fmaf(b_f, c, b_i * b_g);
        float e2 = __builtin_amdgcn_exp2f(-2.0f * LOG2E * c);
        float tc = fmaf(__builtin_amdgcn_rcpf(1.0f + e2), 2.0f, -1.0f);
        float h  = b_o * tc;

        if (p == 0) {
          int qh = (int)__builtin_rintf(h * 127.0f);
          hbuf[nxt][nset] = (char)qh;
          if (nset < 125) {
            int t_orig = dir ? (511 - step) : step;
            h_all[t_orig * 256 + dir * 125 + nset] = (bf16_t)h;
          }
        }
        lds_barrier();
      }
      pv_cur = pv_nxt;
    }
  }

  gridbar(cnt, 2 * NBLK);

  // ===================== P2: qgemm (2048 wave-jobs) =====================
  {
    const int job = blockIdx.x * 8 + wv;        // [0,2048)
    const int bj  = job & 31;
    const int mg  = job >> 5;                   // [0,64)
    const int m   = mg * 16 + cc;               // [0,1024)
    const int j0  = bj * 16;
    const int jA  = j0 + cc;

    const bool isB = (m >= 512);
    const int  row = isB ? (m - 512) : m;
    const int  cof = isB ? 250 : 0;

    f32x4 acc = (f32x4)0.0f;
    #pragma unroll
    for (int ks = 0; ks < 8; ++ks) {
      int kb = 32 * ks + 8 * q;
      bf16x8 a = *(const bf16x8*)&h_all[jA * 256 + kb];
      bf16x8 bfr;
      #pragma unroll
      for (int jj = 0; jj < 8; ++jj) {
        int k = kb + jj;
        float v = (k < 250) ? W1[row * 500 + cof + k] : 0.0f;
        bfr[jj] = (bf16_t)v;
      }
      acc = __builtin_amdgcn_mfma_f32_16x16x32_bf16(a, bfr, acc, 0, 0, 0);
    }

    const float C2 = 2.0f * LOG2E;
    #pragma unroll
    for (int reg = 0; reg < 4; ++reg) {
      int j = j0 + 4 * q + reg;
      float v = acc[reg];
      if (!isB) Ea[j * 512 + m] = __builtin_amdgcn_exp2f(C2 * v);
      else      Eb[j * 512 + (m - 512)] =
                    __builtin_amdgcn_exp2f(C2 * (v + b1[m - 512]));
    }
  }

  gridbar(cnt, 3 * NBLK);

  // ===================== P3: outer (512 half-block jobs) =====================
  {
    __shared__ float sa2[2][2][32][36];   // [half][buf][j][k]
    __shared__ float sb2[2][2][16][36];   // [half][buf][i][k]
    __shared__ float sw[2][2][32];

    const int half = tid >> 8;            // 0,1
    const int t2   = tid & 255;
    const int job  = blockIdx.x * 2 + half;   // [0,512)
    const int bi   = job >> 4, bjx = job & 15;
    const int i0   = bi * 16, j0 = bjx * 32;
    const int ii   = t2 & 15;
    const int jj2  = t2 >> 4;

    const int lj  = t2 & 31, lk4 = (t2 >> 5) * 4;
    const int li  = t2 & 15, lk4b = ((t2 >> 4) & 7) * 4;

    float accR0 = 0.0f, accR1 = 0.0f;
    float wsum = 0.0f;

    for (int kc = 0; kc < 16; ++kc) {
      const int buf = kc & 1;
      const int k0  = kc * 32;
      float4 va = *(const float4*)&Ea[(j0 + lj) * 512 + k0 + lk4];
      *(float4*)&sa2[half][buf][lj][lk4] = va;
      if (t2 < 128) {
        float4 vb = *(const float4*)&Eb[(i0 + li) * 512 + k0 + lk4b];
        *(float4*)&sb2[half][buf][li][lk4b] = vb;
      }
      if (t2 < 32) sw[half][buf][t2] = W2[k0 + t2];
      __syncthreads();

      #pragma unroll 4
      for (int kk = 0; kk < 32; kk += 2) {
        float2 wv2 = *(const float2*)&sw[half][buf][kk];
        float2 bv  = *(const float2*)&sb2[half][buf][ii][kk];
        float2 a0  = *(const float2*)&sa2[half][buf][2 * jj2 + 0][kk];
        float2 a1  = *(const float2*)&sa2[half][buf][2 * jj2 + 1][kk];
        wsum += wv2.x + wv2.y;
        {
          float t1  = fmaf(a0.x, bv.x, 1.0f);
          float tt2 = fmaf(a0.y, bv.y, 1.0f);
          float den = t1 * tt2;
          float num = fmaf(wv2.x, tt2, wv2.y * t1);
          accR0 = fmaf(num, __builtin_amdgcn_rcpf(den), accR0);
        }
        {
          float t1  = fmaf(a1.x, bv.x, 1.0f);
          float tt2 = fmaf(a1.y, bv.y, 1.0f);
          float den = t1 * tt2;
          float num = fmaf(wv2.x, tt2, wv2.y * t1);
          accR1 = fmaf(num, __builtin_amdgcn_rcpf(den), accR1);
        }
      }
    }

    const float bb = b2[0];
    float2 o;
    o.x = wsum - 2.0f * accR0 + bb;
    o.y = wsum - 2.0f * accR1 + bb;
    *(float2*)&out[(i0 + ii) * 512 + j0 + 2 * jj2] = o;
  }
}

// ---------------------------------------------------------------------------
extern "C" void kernel_launch(void* const* d_in, const int* in_sizes, int n_in,
                              void* d_out, int out_size, void* d_ws, size_t ws_size,
                              hipStream_t stream) {
  const float* emb   = (const float*)d_in[0];
  const float* Wih_f = (const float*)d_in[1];
  const float* Whh_f = (const float*)d_in[2];
  const float* bih_f = (const float*)d_in[3];
  const float* bhh_f = (const float*)d_in[4];
  const float* Wih_b = (const float*)d_in[5];
  const float* Whh_b = (const float*)d_in[6];
  const float* bih_b = (const float*)d_in[7];
  const float* bhh_b = (const float*)d_in[8];
  const float* W1    = (const float*)d_in[9];
  const float* b1    = (const float*)d_in[10];
  const float* W2    = (const float*)d_in[11];
  const float* b2    = (const float*)d_in[12];
  float* out = (float*)d_out;

  char* ws = (char*)d_ws;
  float*    pre   = (float*)ws;                                  // 2 MB
  bf16_t*   h_all = (bf16_t*)(ws + 2 * 1024 * 1024);             // 256 KB
  float*    Ea    = (float*)(ws + 2 * 1024 * 1024 + 256 * 1024); // 1 MB
  float*    Eb    = Ea + 512 * 512;                              // 1 MB
  unsigned* cnt   = (unsigned*)(ws + 4 * 1024 * 1024 + 256 * 1024 + 160 * 1024);

  hipMemsetAsync(cnt, 0, 64, stream);
  fused_kernel<<<NBLK, 512, 0, stream>>>(
      emb, Wih_f, bih_f, bhh_f, Wih_b, bih_b, bhh_b,
      Whh_f, Whh_b, W1, b1, W2, b2,
      pre, h_all, Ea, Eb, cnt, out);
}

// Round 6
// 345.329 us; speedup vs baseline: 2.9799x; 2.9799x over previous
//
#include <hip/hip_runtime.h>

typedef __bf16 bf16_t;
typedef __bf16 bf16x8 __attribute__((ext_vector_type(8)));
typedef float f32x4 __attribute__((ext_vector_type(4)));
typedef int   int4v __attribute__((ext_vector_type(4)));

#define LOG2E 1.4426950408889634f
#define NBLK  256

template<int CTRL>
__device__ __forceinline__ float qperm(float x) {
  return __builtin_bit_cast(float,
      __builtin_amdgcn_update_dpp(0, __builtin_bit_cast(int, x), CTRL, 0xF, 0xF, true));
}

// LDS-only barrier: does NOT drain vmcnt, so global loads/stores stay in
// flight across steps (compiler's __syncthreads drains vmcnt(0) every step).
__device__ __forceinline__ void lds_barrier() {
  asm volatile("s_waitcnt lgkmcnt(0)\n\ts_barrier" ::: "memory");
}

// Device-scope grid barrier (agent scope -> cross-XCD safe).  Used ONLY
// between two balanced full-chip phases (skew ~us): round-5 showed that a
// long idle-spin window (254 blocks sleeping ~200us) drops SCLK to the DVFS
// floor and stretches the serial phase ~4x.  Short waits are safe.
__device__ __forceinline__ void gridbar(unsigned* cnt, unsigned target) {
  __syncthreads();
  if (threadIdx.x == 0) {
    __threadfence();
    __hip_atomic_fetch_add(cnt, 1u, __ATOMIC_RELEASE, __HIP_MEMORY_SCOPE_AGENT);
    while (__hip_atomic_load(cnt, __ATOMIC_ACQUIRE, __HIP_MEMORY_SCOPE_AGENT)
           < target)
      __builtin_amdgcn_s_sleep(1);
  }
  __syncthreads();
}

// ---------------------------------------------------------------------------
// K1: preT[dir][r][t] = (Wih_dir @ x[t_x]) + bih + bhh, gate-interleaved rows:
//     r = 4n + p  <->  original row j = 125*p + n   (n<125 valid, else 0)
//     t_x = t (fwd) or 511-t (bwd).
// MFMA GEMM with bf16 hi/lo split (Whi*xhi + Whi*xlo + Wlo*xhi): fp32-exact
// to ~2^-18.  grid = 64 blocks (dir*32 + row-tile T), 256 threads (4 waves),
// each wave does 8 t-tiles of 16.
// ---------------------------------------------------------------------------
__global__ __launch_bounds__(256) void pre_kernel(
    const float* __restrict__ x,     // [512][125]
    const float* __restrict__ Wih_f, const float* __restrict__ bih_f,
    const float* __restrict__ bhh_f,
    const float* __restrict__ Wih_b, const float* __restrict__ bih_b,
    const float* __restrict__ bhh_b,
    float* __restrict__ preT)        // [2][512 r][512 t]
{
  const int dir = blockIdx.x >> 5;
  const int T   = blockIdx.x & 31;
  const float* __restrict__ Wih = dir ? Wih_b : Wih_f;
  const float* __restrict__ bih = dir ? bih_b : bih_f;
  const float* __restrict__ bhh = dir ? bhh_b : bhh_f;

  const int tid = threadIdx.x;
  const int wv  = tid >> 6;
  const int lane = tid & 63;
  const int q = lane >> 4, cc = lane & 15;

  // A fragments for row-tile T: row r = 16T + cc, k = 32ks + 8q + j
  const int r  = 16 * T + cc;
  const int na = r >> 2, pa = r & 3;
  const bool vld = (na < 125);
  const float* __restrict__ Wr = Wih + (vld ? (125 * pa + na) * 125 : 0);

  bf16x8 whi[4], wlo[4];
  #pragma unroll
  for (int ks = 0; ks < 4; ++ks) {
    #pragma unroll
    for (int j = 0; j < 8; ++j) {
      int k = 32 * ks + 8 * q + j;
      float wvv = (vld && k < 125) ? Wr[k] : 0.0f;
      bf16_t hi = (bf16_t)wvv;
      whi[ks][j] = hi;
      wlo[ks][j] = (bf16_t)(wvv - (float)hi);
    }
  }

  // bias for the 4 output rows this lane stores
  float bias[4];
  #pragma unroll
  for (int reg = 0; reg < 4; ++reg) {
    int ro = 16 * T + 4 * q + reg;
    int no = ro >> 2, po = ro & 3;
    bias[reg] = (no < 125) ? (bih[125 * po + no] + bhh[125 * po + no]) : 0.0f;
  }

  for (int i = 0; i < 8; ++i) {
    const int tt = 8 * wv + i;
    const int t  = 16 * tt + cc;
    const int trow = dir ? (511 - t) : t;
    const float* __restrict__ xr = x + trow * 125;

    f32x4 acc = (f32x4)0.0f;
    #pragma unroll
    for (int ks = 0; ks < 4; ++ks) {
      bf16x8 xhi, xlo;
      #pragma unroll
      for (int j = 0; j < 8; ++j) {
        int k = 32 * ks + 8 * q + j;
        float xv = (k < 125) ? xr[k] : 0.0f;
        bf16_t hi = (bf16_t)xv;
        xhi[j] = hi;
        xlo[j] = (bf16_t)(xv - (float)hi);
      }
      acc = __builtin_amdgcn_mfma_f32_16x16x32_bf16(whi[ks], xhi, acc, 0, 0, 0);
      acc = __builtin_amdgcn_mfma_f32_16x16x32_bf16(whi[ks], xlo, acc, 0, 0, 0);
      acc = __builtin_amdgcn_mfma_f32_16x16x32_bf16(wlo[ks], xhi, acc, 0, 0, 0);
    }
    #pragma unroll
    for (int reg = 0; reg < 4; ++reg) {
      int ro = 16 * T + 4 * q + reg;
      preT[dir * 262144 + ro * 512 + 16 * tt + cc] = acc[reg] + bias[reg];
    }
  }
}

// ---------------------------------------------------------------------------
// K2: sequential LSTM.  grid = 2 blocks (dir), 512 threads (8 waves).
// Whh@h via mfma_i32_16x16x64_i8 (int8 quantized: h scale 127 exact since
// |h|<1; W global scale 127/max|W| computed on-device).  int32 accumulate is
// exact; dequant folded into the exp2 multiplier.
// Lane 16q + 4lt + p owns gate p of unit n = 16w + 4lt + q.
// (Round-0 proven structure: MFMA keeps the VALU dependency chain short —
// dot4 variants measured 18-22% slower on the latency-bound serial step.)
// ---------------------------------------------------------------------------
__global__ __launch_bounds__(512) void lstm_kernel(
    const float* __restrict__ Whh_f, const float* __restrict__ Whh_b,
    const float* __restrict__ pre,   // [2][512 r][512 t]
    bf16_t* __restrict__ h_all)      // [512][256]  (0:125 fwd | 125:250 bwd | 250:256 zero)
{
  const int dir = blockIdx.x;
  const float* __restrict__ Whh = dir ? Whh_b : Whh_f;

  const int tid  = threadIdx.x;
  const int lane = tid & 63;
  const int w    = tid >> 6;      // wave 0..7
  const int q    = lane >> 4;     // 0..3
  const int cc   = lane & 15;
  const int lt   = cc >> 2;       // local tile 0..3
  const int p    = cc & 3;        // gate index

  // ---- pass 1: global max |Whh| over used elements ----
  float wm = 0.0f;
  #pragma unroll
  for (int LT = 0; LT < 4; ++LT) {
    int rr = 16 * (4 * w + LT) + cc;
    int nn = rr >> 2, pp = rr & 3;
    if (nn < 125) {
      const float* __restrict__ Wrow = Whh + (125 * pp + nn) * 125;
      #pragma unroll
      for (int ks = 0; ks < 2; ++ks)
        #pragma unroll
        for (int jj = 0; jj < 16; ++jj) {
          int k = 64 * ks + 16 * q + jj;
          if (k < 125) wm = fmaxf(wm, fabsf(Wrow[k]));
        }
    }
  }
  #pragma unroll
  for (int off = 1; off < 64; off <<= 1)
    wm = fmaxf(wm, __shfl_xor(wm, off));
  __shared__ float wmx[8];
  if (lane == 0) wmx[w] = wm;
  __syncthreads();
  float wmax = wmx[0];
  #pragma unroll
  for (int u = 1; u < 8; ++u) wmax = fmaxf(wmax, wmx[u]);
  const float s_w  = 127.0f / wmax;
  const float invq = wmax / (127.0f * 127.0f);   // D -> W@h

  // ---- pass 2: quantize A fragments (i8, k = 64ks + 16q + jj) ----
  int4v afrag[4][2];
  #pragma unroll
  for (int LT = 0; LT < 4; ++LT) {
    int rr = 16 * (4 * w + LT) + cc;
    int nn = rr >> 2, pp = rr & 3;
    bool avld = (nn < 125);
    const float* __restrict__ Wrow = Whh + (avld ? (125 * pp + nn) * 125 : 0);
    #pragma unroll
    for (int ks = 0; ks < 2; ++ks) {
      int4v v;
      #pragma unroll
      for (int word = 0; word < 4; ++word) {
        int b = 0;
        #pragma unroll
        for (int byte = 0; byte < 4; ++byte) {
          int jj = 4 * word + byte;
          int k  = 64 * ks + 16 * q + jj;
          int qv = 0;
          if (avld && k < 125)
            qv = (int)__builtin_rintf(Wrow[k] * s_w);
          b |= (qv & 0xFF) << (8 * byte);
        }
        v[word] = b;
      }
      afrag[LT][ks] = v;
    }
  }

  __shared__ __align__(16) char hbuf[2][128];    // int8 h, double buffered
  if (tid < 256) hbuf[tid >> 7][tid & 127] = 0;
  // zero h_all pad columns once (dir 0 only)
  if (dir == 0) {
    #pragma unroll
    for (int u = 0; u < 6; ++u) h_all[tid * 256 + 250 + u] = (bf16_t)0.0f;
  }
  __syncthreads();

  const int   r_lane = 64 * w + 16 * lt + 4 * q + p;
  const int   nset   = 16 * w + 4 * lt + q;
  const float mult   = (p == 2) ? (-2.0f * LOG2E) : (-LOG2E);
  const float sA     = (p == 2) ? 2.0f : 1.0f;
  const float sB     = (p == 2) ? -1.0f : 0.0f;
  const float dscale = mult * invq;              // int D -> exp2 argument
  const float* __restrict__ preR = pre + dir * 262144 + r_lane * 512;
  float c = 0.0f;

  float4 pv_cur = *(const float4*)preR;

  for (int g = 0; g < 128; ++g) {
    float4 pv_nxt = make_float4(0.f, 0.f, 0.f, 0.f);
    if (g < 127) pv_nxt = *(const float4*)(preR + 4 * (g + 1));

    #pragma unroll
    for (int s4 = 0; s4 < 4; ++s4) {
      const int step = 4 * g + s4;
      const int cur  = s4 & 1, nxt = cur ^ 1;
      const float pv = (s4 == 0) ? pv_cur.x : (s4 == 1) ? pv_cur.y
                     : (s4 == 2) ? pv_cur.z : pv_cur.w;
      const float pvm = mult * pv;               // off critical path

      int4v b0 = *(const int4v*)&hbuf[cur][16 * q];
      int4v b1 = *(const int4v*)&hbuf[cur][64 + 16 * q];

      int4v acc[4];
      #pragma unroll
      for (int LT = 0; LT < 4; ++LT) {
        int4v a = (int4v)0;
        a = __builtin_amdgcn_mfma_i32_16x16x64_i8(afrag[LT][0], b0, a, 0, 0, 0);
        a = __builtin_amdgcn_mfma_i32_16x16x64_i8(afrag[LT][1], b1, a, 0, 0, 0);
        acc[LT] = a;
      }

      // select D for (lt, p) from own registers
      int gl[4];
      #pragma unroll
      for (int LT = 0; LT < 4; ++LT) {
        int a01 = (p & 1) ? acc[LT][1] : acc[LT][0];
        int a23 = (p & 1) ? acc[LT][3] : acc[LT][2];
        gl[LT] = (p & 2) ? a23 : a01;
      }
      int b01 = (lt & 1) ? gl[1] : gl[0];
      int b23 = (lt & 1) ? gl[3] : gl[2];
      int gsel = (lt & 2) ? b23 : b01;

      // uniform activation: y = sigmoid(scale*(W@h + pv)); act = sA*y + sB
      float gf  = (float)gsel;
      float xg  = fmaf(gf, dscale, pvm);
      float e   = __builtin_amdgcn_exp2f(xg);
      float y   = __builtin_amdgcn_rcpf(1.0f + e);
      float act = fmaf(y, sA, sB);

      // quad: p0=i, p1=f, p2=g~, p3=o  (flat broadcast tree)
      float b_i = qperm<0x00>(act);
      float b_f = qperm<0x55>(act);
      float b_g = qperm<0xAA>(act);
      float b_o = qperm<0xFF>(act);
      c = fmaf(b_f, c, b_i * b_g);               // c = f*c + i*g~
      float e2 = __builtin_amdgcn_exp2f(-2.0f * LOG2E * c);
      float tc = fmaf(__builtin_amdgcn_rcpf(1.0f + e2), 2.0f, -1.0f);
      float h  = b_o * tc;

      if (p == 0) {
        int qh = (int)__builtin_rintf(h * 127.0f);
        hbuf[nxt][nset] = (char)qh;              // pad units stay exactly 0
        if (nset < 125) {
          int t_orig = dir ? (511 - step) : step;
          h_all[t_orig * 256 + dir * 125 + nset] = (bf16_t)h;
        }
      }
      lds_barrier();
    }
    pv_cur = pv_nxt;
  }
}

// ---------------------------------------------------------------------------
// K3 (fused tail): phase A = qgemm (Ea/Eb = exp2 of MLP pre-activations),
// phase B = outer reduction.  One grid barrier between them — both phases
// are balanced across all 256 blocks, so barrier skew is ~us (no DVFS trap).
// Saves one kernel-launch gap and keeps Ea/Eb warm in L2 for phase B.
// ---------------------------------------------------------------------------
__global__ __launch_bounds__(512) void tail_kernel(
    const bf16_t* __restrict__ h_all, // [512][256]
    const float* __restrict__ W1,     // [512][500]
    const float* __restrict__ b1,     // [512]
    const float* __restrict__ W2, const float* __restrict__ b2,
    float* __restrict__ Ea,           // [512][512]
    float* __restrict__ Eb,           // [512][512]
    unsigned* __restrict__ cnt,
    float* __restrict__ out)          // [512][512]
{
  const int tid  = threadIdx.x;
  const int wv   = tid >> 6;
  const int lane = tid & 63;
  const int q    = lane >> 4, cc = lane & 15;

  __shared__ float sa2[2][2][32][36];   // [half][buf][j][k]
  __shared__ float sb2[2][2][16][36];   // [half][buf][i][k]
  __shared__ float sw[2][2][32];

  // ===== phase A: qgemm (2048 wave-jobs on 2048 wave-slots) =====
  {
    const int job = blockIdx.x * 8 + wv;        // [0,2048)
    const int bj  = job & 31;
    const int mg  = job >> 5;                   // [0,64)
    const int m   = mg * 16 + cc;               // [0,1024)
    const int j0  = bj * 16;
    const int jA  = j0 + cc;

    const bool isB = (m >= 512);
    const int  row = isB ? (m - 512) : m;
    const int  cof = isB ? 250 : 0;

    f32x4 acc = (f32x4)0.0f;
    #pragma unroll
    for (int ks = 0; ks < 8; ++ks) {
      int kb = 32 * ks + 8 * q;
      bf16x8 a = *(const bf16x8*)&h_all[jA * 256 + kb];
      bf16x8 bfr;
      #pragma unroll
      for (int jj = 0; jj < 8; ++jj) {
        int k = kb + jj;
        float v = (k < 250) ? W1[row * 500 + cof + k] : 0.0f;
        bfr[jj] = (bf16_t)v;
      }
      acc = __builtin_amdgcn_mfma_f32_16x16x32_bf16(a, bfr, acc, 0, 0, 0);
    }

    const float C2 = 2.0f * LOG2E;
    #pragma unroll
    for (int reg = 0; reg < 4; ++reg) {
      int j = j0 + 4 * q + reg;
      float v = acc[reg];
      if (!isB) Ea[j * 512 + m] = __builtin_amdgcn_exp2f(C2 * v);
      else      Eb[j * 512 + (m - 512)] =
                    __builtin_amdgcn_exp2f(C2 * (v + b1[m - 512]));
    }
  }

  gridbar(cnt, NBLK);

  // ===== phase B: outer (512 half-block jobs) =====
  {
    const int half = tid >> 8;            // 0,1
    const int t2   = tid & 255;
    const int job  = blockIdx.x * 2 + half;   // [0,512)
    const int bi   = job >> 4, bjx = job & 15;
    const int i0   = bi * 16, j0 = bjx * 32;
    const int ii   = t2 & 15;
    const int jj2  = t2 >> 4;

    const int lj  = t2 & 31, lk4 = (t2 >> 5) * 4;
    const int li  = t2 & 15, lk4b = ((t2 >> 4) & 7) * 4;

    float accR0 = 0.0f, accR1 = 0.0f;
    float wsum = 0.0f;

    for (int kc = 0; kc < 16; ++kc) {
      const int buf = kc & 1;
      const int k0  = kc * 32;
      float4 va = *(const float4*)&Ea[(j0 + lj) * 512 + k0 + lk4];
      *(float4*)&sa2[half][buf][lj][lk4] = va;
      if (t2 < 128) {
        float4 vb = *(const float4*)&Eb[(i0 + li) * 512 + k0 + lk4b];
        *(float4*)&sb2[half][buf][li][lk4b] = vb;
      }
      if (t2 < 32) sw[half][buf][t2] = W2[k0 + t2];
      __syncthreads();

      #pragma unroll 4
      for (int kk = 0; kk < 32; kk += 2) {
        float2 wv2 = *(const float2*)&sw[half][buf][kk];
        float2 bv  = *(const float2*)&sb2[half][buf][ii][kk];
        float2 a0  = *(const float2*)&sa2[half][buf][2 * jj2 + 0][kk];
        float2 a1  = *(const float2*)&sa2[half][buf][2 * jj2 + 1][kk];
        wsum += wv2.x + wv2.y;
        {
          float t1  = fmaf(a0.x, bv.x, 1.0f);
          float tt2 = fmaf(a0.y, bv.y, 1.0f);
          float den = t1 * tt2;
          float num = fmaf(wv2.x, tt2, wv2.y * t1);
          accR0 = fmaf(num, __builtin_amdgcn_rcpf(den), accR0);
        }
        {
          float t1  = fmaf(a1.x, bv.x, 1.0f);
          float tt2 = fmaf(a1.y, bv.y, 1.0f);
          float den = t1 * tt2;
          float num = fmaf(wv2.x, tt2, wv2.y * t1);
          accR1 = fmaf(num, __builtin_amdgcn_rcpf(den), accR1);
        }
      }
    }

    const float bb = b2[0];
    float2 o;
    o.x = wsum - 2.0f * accR0 + bb;
    o.y = wsum - 2.0f * accR1 + bb;
    *(float2*)&out[(i0 + ii) * 512 + j0 + 2 * jj2] = o;
  }
}

// ---------------------------------------------------------------------------
extern "C" void kernel_launch(void* const* d_in, const int* in_sizes, int n_in,
                              void* d_out, int out_size, void* d_ws, size_t ws_size,
                              hipStream_t stream) {
  const float* emb   = (const float*)d_in[0];
  const float* Wih_f = (const float*)d_in[1];
  const float* Whh_f = (const float*)d_in[2];
  const float* bih_f = (const float*)d_in[3];
  const float* bhh_f = (const float*)d_in[4];
  const float* Wih_b = (const float*)d_in[5];
  const float* Whh_b = (const float*)d_in[6];
  const float* bih_b = (const float*)d_in[7];
  const float* bhh_b = (const float*)d_in[8];
  const float* W1    = (const float*)d_in[9];
  const float* b1    = (const float*)d_in[10];
  const float* W2    = (const float*)d_in[11];
  const float* b2    = (const float*)d_in[12];
  float* out = (float*)d_out;

  char* ws = (char*)d_ws;
  float*    pre   = (float*)ws;                                  // 2 MB
  bf16_t*   h_all = (bf16_t*)(ws + 2 * 1024 * 1024);             // 256 KB
  float*    Ea    = (float*)(ws + 2 * 1024 * 1024 + 256 * 1024); // 1 MB
  float*    Eb    = Ea + 512 * 512;                              // 1 MB
  unsigned* cnt   = (unsigned*)(ws + 4 * 1024 * 1024 + 256 * 1024 + 160 * 1024);

  hipMemsetAsync(cnt, 0, 64, stream);
  pre_kernel<<<64, 256, 0, stream>>>(emb, Wih_f, bih_f, bhh_f,
                                     Wih_b, bih_b, bhh_b, pre);
  lstm_kernel<<<2, 512, 0, stream>>>(Whh_f, Whh_b, pre, h_all);
  tail_kernel<<<NBLK, 512, 0, stream>>>(h_all, W1, b1, W2, b2,
                                        Ea, Eb, cnt, out);
}